// Round 5
// baseline (186.986 us; speedup 1.0000x reference)
//
#include <hip/hip_runtime.h>

typedef __attribute__((ext_vector_type(8))) _Float16 f16x8;
typedef __attribute__((ext_vector_type(4))) _Float16 f16x4;
typedef __attribute__((ext_vector_type(2))) __fp16 fp16v2;  // cvt_pkrtz result type
typedef __attribute__((ext_vector_type(4))) float f32x4;

#define NB 16
#define MAXC 256
#define MAXT 4096
#define HID 512
#define NSRC 256
#define TT 64

// Barrier WITHOUT vmcnt drain: LDS writes (lgkm) must be visible, but
// register-destined global loads may stay in flight across the barrier.
// The "memory" clobber also pins pre-issued loads on the issue side.
#define BAR() asm volatile("s_waitcnt lgkmcnt(0)\n\ts_barrier" ::: "memory")

#define MFMA(a, b, c) __builtin_amdgcn_mfma_f32_16x16x32_f16(a, b, c, 0, 0, 0)

// gelu(x) ~= x * sigmoid(1.5957691x + 0.0713548x^3)   (tanh-form, |err| ~3e-4)
__device__ __forceinline__ float gelu_fast(float x) {
  float p = x * x;
  float q = __builtin_fmaf(p, -0.10294336f, -2.30220778f);
  float e = __builtin_amdgcn_exp2f(x * q);
  return x * __builtin_amdgcn_rcpf(1.0f + e);
}

// (R x C) fp32 -> (C x R) fp16, one 32x32 tile per block, blockIdx.z = matrix idx
__global__ void transpose_cvt_kernel(const float* __restrict__ src,
                                     _Float16* __restrict__ dst, int R, int C) {
  __shared__ float tile[32][33];
  const float* s = src + (size_t)blockIdx.z * R * C;
  _Float16* d = dst + (size_t)blockIdx.z * R * C;
  int c0 = blockIdx.x * 32, r0 = blockIdx.y * 32;
  int tx = threadIdx.x, ty = threadIdx.y;
  for (int i = ty; i < 32; i += 8)
    tile[i][tx] = s[(size_t)(r0 + i) * C + (c0 + tx)];
  __syncthreads();
  for (int i = ty; i < 32; i += 8)
    d[(size_t)(c0 + i) * R + (r0 + tx)] = (_Float16)tile[tx][i];
}

// Persistent-ish WG: grid = 256 WGs (1/CU), each owns (b = g>>4) and 4
// adjacent 64-t tiles: tile indices (g&15)*4 + 0..3.  Per tile:
//   write Xs(i) | issue x-loads(i+1) | BAR | G1(K=256, mi=4 ni=4) | gelu->Hs
//   | prefetch W2 | BAR | G2(K=512, 4sb x 2tb, mi=4 ni=2) | store
// x-loads for tile i+1 ride across both barriers and a full compute phase
// (~9k cyc) -- HBM latency fully hidden.
__global__ __launch_bounds__(512, 2)
void fused_sess_proj_kernel(const float* __restrict__ x,
                            const int* __restrict__ sess_ids,
                            const int* __restrict__ seq_lens,
                            const _Float16* __restrict__ W1t,   // [8][HID][MAXC]
                            const float* __restrict__ b_sess,   // [8][HID]
                            const _Float16* __restrict__ W2t,   // [NSRC][HID]
                            const float* __restrict__ b2,       // [NSRC]
                            float* __restrict__ out) {
  int g = blockIdx.x;
  int b = g >> 4;
  int tile0 = (g & 15) * 4;
  int seqlen = seq_lens[b];
  int sid = sess_ids[b];
  int tid = threadIdx.x;
  int lane = tid & 63;
  int w = tid >> 6;    // wave 0..7
  int lg = lane >> 4;  // k-group / acc row-group
  int lr = lane & 15;  // m-row (A) / n-col (B,D)
  int sb = w >> 1;     // GEMM2: s-block (64 rows)
  int tb = w & 1;      // GEMM2: t-half (32 t)
  const _Float16* W1s = W1t + (size_t)sid * HID * MAXC;

  // swizzled [t][col] layouts: f16 idx = t*W + (col ^ ((t&7)<<3))
  __shared__ _Float16 Xs[TT * MAXC];  // 32 KB (single buffer -- safe by barrier rendezvous)
  __shared__ _Float16 Hs[TT * HID];   // 64 KB (full 512 h rows)

  // staging registers: 2 channels x 16 t per thread
  int c2 = (tid & 127) * 2;
  int th = tid >> 7;  // 0..3 -> t-slice [th*16, th*16+16)
  f32x4 va[4], vb[4];

  bool act0 = (tile0 * TT) < seqlen;
  if (act0) {
    const float* xp = x + ((size_t)b * MAXC + c2) * MAXT + tile0 * TT + th * 16;
    #pragma unroll
    for (int i = 0; i < 4; ++i) va[i] = *(const f32x4*)(xp + i * 4);
    #pragma unroll
    for (int i = 0; i < 4; ++i) vb[i] = *(const f32x4*)(xp + MAXT + i * 4);
  }

  f16x8 AF[2][4];  // rolling A-fragment prefetch (shared by G1/G2 sequentially)

  #pragma unroll 1
  for (int it = 0; it < 4; ++it) {
    int t0 = (tile0 + it) * TT;
    bool act = t0 < seqlen;               // wg-uniform
    bool actn = (it < 3) && (t0 + TT < seqlen);

    f32x4 acc1[4][4];
    if (act) {
      // ---- commit staged x (tile it) to Xs ----
      #pragma unroll
      for (int k = 0; k < 16; ++k) {
        int t = th * 16 + k;
        fp16v2 p = __builtin_amdgcn_cvt_pkrtz(va[k >> 2][k & 3], vb[k >> 2][k & 3]);
        *(fp16v2*)(&Xs[t * 256 + (c2 ^ ((t & 7) << 3))]) = p;
      }
      // ---- issue x loads for tile it+1 (hidden under this tile's compute) ----
      if (actn) {
        const float* xp = x + ((size_t)b * MAXC + c2) * MAXT + t0 + TT + th * 16;
        #pragma unroll
        for (int i = 0; i < 4; ++i) va[i] = *(const f32x4*)(xp + i * 4);
        #pragma unroll
        for (int i = 0; i < 4; ++i) vb[i] = *(const f32x4*)(xp + MAXT + i * 4);
      }
      // ---- prefetch G1 A-frags ks=0,1 + bias (in flight across BAR) ----
      #pragma unroll
      for (int mi = 0; mi < 4; ++mi) {
        AF[0][mi] = *(const f16x8*)(W1s + (size_t)(w * 64 + mi * 16 + lr) * MAXC + lg * 8);
        AF[1][mi] = *(const f16x8*)(W1s + (size_t)(w * 64 + mi * 16 + lr) * MAXC + 32 + lg * 8);
      }
      #pragma unroll
      for (int mi = 0; mi < 4; ++mi) {
        f32x4 bv = *(const f32x4*)(b_sess + sid * HID + w * 64 + mi * 16 + lg * 4);
        #pragma unroll
        for (int ni = 0; ni < 4; ++ni) acc1[mi][ni] = bv;
      }
    }
    BAR();  // Xs visible; prev iter's Hs readers done

    if (act) {
      // ================= GEMM1: h[w*64..+64][64t], K=256 =================
      #pragma unroll
      for (int ks = 0; ks < 8; ++ks) {
        f16x8 a[4];
        #pragma unroll
        for (int mi = 0; mi < 4; ++mi) a[mi] = AF[ks & 1][mi];
        if (ks < 6) {
          #pragma unroll
          for (int mi = 0; mi < 4; ++mi)
            AF[ks & 1][mi] = *(const f16x8*)(W1s +
                (size_t)(w * 64 + mi * 16 + lr) * MAXC + (ks + 2) * 32 + lg * 8);
        }
        f16x8 bf[4];
        #pragma unroll
        for (int ni = 0; ni < 4; ++ni) {
          int t = ni * 16 + lr;
          bf[ni] = *(const f16x8*)(&Xs[t * 256 + ((ks * 32 + lg * 8) ^ ((t & 7) << 3))]);
        }
        #pragma unroll
        for (int mi = 0; mi < 4; ++mi)
          #pragma unroll
          for (int ni = 0; ni < 4; ++ni)
            acc1[mi][ni] = MFMA(a[mi], bf[ni], acc1[mi][ni]);
      }
      // ---- gelu -> Hs (512-wide swizzled) ----
      #pragma unroll
      for (int mi = 0; mi < 4; ++mi) {
        int hh = w * 64 + mi * 16 + lg * 4;
        #pragma unroll
        for (int ni = 0; ni < 4; ++ni) {
          int t = ni * 16 + lr;
          f16x4 gv;
          #pragma unroll
          for (int r = 0; r < 4; ++r) gv[r] = (_Float16)gelu_fast(acc1[mi][ni][r]);
          *(f16x4*)(&Hs[t * 512 + (hh ^ ((t & 7) << 3))]) = gv;
        }
      }
    }
    f32x4 acc2[4][2];
    if (act) {
      // ---- prefetch G2 A-frags ks=0,1 + bias (in flight across BAR) ----
      #pragma unroll
      for (int mi = 0; mi < 4; ++mi) {
        AF[0][mi] = *(const f16x8*)(W2t + (size_t)(sb * 64 + mi * 16 + lr) * HID + lg * 8);
        AF[1][mi] = *(const f16x8*)(W2t + (size_t)(sb * 64 + mi * 16 + lr) * HID + 32 + lg * 8);
      }
      #pragma unroll
      for (int mi = 0; mi < 4; ++mi) {
        f32x4 bv = *(const f32x4*)(b2 + sb * 64 + mi * 16 + lg * 4);
        acc2[mi][0] = bv;
        acc2[mi][1] = bv;
      }
    }
    BAR();  // Hs visible

    if (act) {
      // ================= GEMM2: out[sb*64..+64][tb*32..+32], K=512 =================
      #pragma unroll
      for (int ks = 0; ks < 16; ++ks) {
        f16x8 a[4];
        #pragma unroll
        for (int mi = 0; mi < 4; ++mi) a[mi] = AF[ks & 1][mi];
        if (ks < 14) {
          #pragma unroll
          for (int mi = 0; mi < 4; ++mi)
            AF[ks & 1][mi] = *(const f16x8*)(W2t +
                (size_t)(sb * 64 + mi * 16 + lr) * HID + (ks + 2) * 32 + lg * 8);
        }
        f16x8 bf[2];
        #pragma unroll
        for (int ni = 0; ni < 2; ++ni) {
          int t = tb * 32 + ni * 16 + lr;
          bf[ni] = *(const f16x8*)(&Hs[t * 512 + ((ks * 32 + lg * 8) ^ ((t & 7) << 3))]);
        }
        #pragma unroll
        for (int mi = 0; mi < 4; ++mi)
          #pragma unroll
          for (int ni = 0; ni < 2; ++ni)
            acc2[mi][ni] = MFMA(a[mi], bf[ni], acc2[mi][ni]);
      }
      // ---- epilogue: time mask + fp32 store ----
      #pragma unroll
      for (int mi = 0; mi < 4; ++mi) {
        int s0 = sb * 64 + mi * 16 + lg * 4;
        #pragma unroll
        for (int ni = 0; ni < 2; ++ni) {
          int t = t0 + tb * 32 + ni * 16 + lr;
          float m = (t < seqlen) ? 1.0f : 0.0f;
          #pragma unroll
          for (int r = 0; r < 4; ++r)
            out[((size_t)b * NSRC + s0 + r) * MAXT + t] = acc2[mi][ni][r] * m;
        }
      }
    } else {
      // fully masked tile: write zeros (d_out is poisoned)
      int row = tid >> 1;
      int part = tid & 1;
      float* po = out + ((size_t)b * NSRC + row) * MAXT + t0 + part * 32;
      f32x4 z = {0.f, 0.f, 0.f, 0.f};
      #pragma unroll
      for (int i = 0; i < 8; ++i) *(f32x4*)(po + i * 4) = z;
    }
  }
}

extern "C" void kernel_launch(void* const* d_in, const int* in_sizes, int n_in,
                              void* d_out, int out_size, void* d_ws, size_t ws_size,
                              hipStream_t stream) {
  const float* x      = (const float*)d_in[0];
  const int* sess     = (const int*)d_in[1];
  // d_in[2] = channel_counts: unused (x is already zero-padded past true channels)
  const int* seq      = (const int*)d_in[3];
  const float* W_sess = (const float*)d_in[4];
  const float* b_sess = (const float*)d_in[5];
  const float* W2     = (const float*)d_in[6];
  const float* b2     = (const float*)d_in[7];
  float* out = (float*)d_out;

  _Float16* W1t = (_Float16*)d_ws;                               // [8][512][256]
  _Float16* W2t = (_Float16*)((char*)d_ws + (size_t)8 * HID * MAXC * sizeof(_Float16));

  dim3 tb(32, 8);
  // W_sess: per session (256 x 512) -> (512 x 256) fp16
  transpose_cvt_kernel<<<dim3(HID / 32, MAXC / 32, 8), tb, 0, stream>>>(W_sess, W1t, MAXC, HID);
  // W2: (512 x 256) -> (256 x 512) fp16
  transpose_cvt_kernel<<<dim3(NSRC / 32, HID / 32, 1), tb, 0, stream>>>(W2, W2t, HID, NSRC);

  fused_sess_proj_kernel<<<dim3(256), dim3(512), 0, stream>>>(
      x, sess, seq, W1t, b_sess, W2t, b2, out);
}

// Round 6
// 150.281 us; speedup vs baseline: 1.2442x; 1.2442x over previous
//
#include <hip/hip_runtime.h>

typedef __attribute__((ext_vector_type(8))) _Float16 f16x8;
typedef __attribute__((ext_vector_type(4))) _Float16 f16x4;
typedef __attribute__((ext_vector_type(2))) __fp16 fp16v2;  // cvt_pkrtz result type
typedef __attribute__((ext_vector_type(4))) float f32x4;
typedef __attribute__((ext_vector_type(16))) float f32x16;

#define NB 16
#define MAXC 256
#define MAXT 4096
#define HID 512
#define NSRC 256
#define TT 32   // time-tile per WG

// Barrier WITHOUT vmcnt drain: LDS writes (lgkm) must be visible, but
// register-destined global loads may stay in flight across the barrier.
#define BAR() asm volatile("s_waitcnt lgkmcnt(0)\n\ts_barrier" ::: "memory")

#define MFMA32(a, b, c) __builtin_amdgcn_mfma_f32_32x32x16_f16(a, b, c, 0, 0, 0)

// swizzled [t][col] layout, row = 256 f16: idx = t*256 + (col ^ ((t&31)<<3))
__device__ __forceinline__ int swz(int t, int col) {
  return t * 256 + (col ^ ((t & 31) << 3));
}

// gelu(x) ~= x * sigmoid(1.5957691x + 0.0713548x^3)   (tanh-form, |err| ~3e-4)
__device__ __forceinline__ float gelu_fast(float x) {
  float p = x * x;
  float q = __builtin_fmaf(p, -0.10294336f, -2.30220778f);
  float e = __builtin_amdgcn_exp2f(x * q);
  return x * __builtin_amdgcn_rcpf(1.0f + e);
}

// (R x C) fp32 -> (C x R) fp16, one 32x32 tile per block, blockIdx.z = matrix idx
__global__ void transpose_cvt_kernel(const float* __restrict__ src,
                                     _Float16* __restrict__ dst, int R, int C) {
  __shared__ float tile[32][33];
  const float* s = src + (size_t)blockIdx.z * R * C;
  _Float16* d = dst + (size_t)blockIdx.z * R * C;
  int c0 = blockIdx.x * 32, r0 = blockIdx.y * 32;
  int tx = threadIdx.x, ty = threadIdx.y;
  for (int i = ty; i < 32; i += 8)
    tile[i][tx] = s[(size_t)(r0 + i) * C + (c0 + tx)];
  __syncthreads();
  for (int i = ty; i < 32; i += 8)
    d[(size_t)(c0 + i) * R + (r0 + tx)] = (_Float16)tile[tx][i];
}

// One WG = one (batch, 32-t tile). 4 waves, 32 KB LDS -> 4 WGs/CU resident.
// 32x32x16 MFMA: wave computes 64 h-rows (G1) / 64 s-rows (G2) x 32 t.
__global__ __launch_bounds__(256, 4)
void fused_sess_proj_kernel(const float* __restrict__ x,
                            const int* __restrict__ sess_ids,
                            const int* __restrict__ seq_lens,
                            const _Float16* __restrict__ W1t,   // [8][HID][MAXC]
                            const float* __restrict__ b_sess,   // [8][HID]
                            const _Float16* __restrict__ W2t,   // [NSRC][HID]
                            const float* __restrict__ b2,       // [NSRC]
                            float* __restrict__ out) {
  int wg = blockIdx.x;
  int b = wg >> 7;            // 128 tiles per batch
  int t0 = (wg & 127) * TT;
  int seqlen = seq_lens[b];
  int tid = threadIdx.x;

  if (t0 >= seqlen) {  // fully masked tile: write zeros (d_out is poisoned)
    float* po = out + ((size_t)b * NSRC + tid) * MAXT + t0;
    f32x4 z = {0.f, 0.f, 0.f, 0.f};
    #pragma unroll
    for (int i = 0; i < 8; ++i) *(f32x4*)(po + i * 4) = z;
    return;
  }

  __shared__ _Float16 Xs[TT * MAXC];  // 16 KB
  __shared__ _Float16 Hs[TT * 256];   // 16 KB (one 256-h chunk at a time)

  int lane = tid & 63;
  int w = tid >> 6;    // wave 0..3
  int lm = lane & 31;  // row (A) / col=t (B, D)
  int kl = lane >> 5;  // k-half
  int sid = sess_ids[b];
  const _Float16* W1s = W1t + (size_t)sid * HID * MAXC;

  // ---- stage X^T tile as fp16: channel-pair x 16t per thread, dword writes ----
  {
    int c2 = (tid & 127) * 2;
    int th = tid >> 7;  // t-half (wave-uniform)
    const float* xp = x + ((size_t)b * MAXC + c2) * MAXT + t0 + th * 16;
    #pragma unroll
    for (int half = 0; half < 2; ++half) {
      f32x4 va[2], vb[2];
      #pragma unroll
      for (int i = 0; i < 2; ++i) va[i] = *(const f32x4*)(xp + half * 8 + i * 4);
      #pragma unroll
      for (int i = 0; i < 2; ++i) vb[i] = *(const f32x4*)(xp + MAXT + half * 8 + i * 4);
      #pragma unroll
      for (int k = 0; k < 8; ++k) {
        int t = th * 16 + half * 8 + k;
        fp16v2 p = __builtin_amdgcn_cvt_pkrtz(va[k >> 2][k & 3], vb[k >> 2][k & 3]);
        *(fp16v2*)(&Xs[swz(t, c2)]) = p;
      }
    }
  }
  BAR();  // Xs visible

  f32x16 acc2[2];

  #pragma unroll
  for (int ch = 0; ch < 2; ++ch) {
    int chb = ch * 256;

    // ---- GEMM1 chunk: h rows [chb + w*64, +64), bias-init ----
    f32x16 acc1[2];
    #pragma unroll
    for (int mi = 0; mi < 2; ++mi)
      #pragma unroll
      for (int q = 0; q < 4; ++q) {
        f32x4 bv = *(const f32x4*)(b_sess + sid * HID + chb + w * 64 + mi * 32 + q * 8 + kl * 4);
        #pragma unroll
        for (int r = 0; r < 4; ++r) acc1[mi][q * 4 + r] = bv[r];
      }

    const _Float16* w1p = W1s + (size_t)(chb + w * 64 + lm) * MAXC + kl * 8;
    #pragma unroll
    for (int ks = 0; ks < 16; ++ks) {
      f16x8 af0 = *(const f16x8*)(w1p + ks * 16);
      f16x8 af1 = *(const f16x8*)(w1p + 32 * MAXC + ks * 16);
      f16x8 bf = *(const f16x8*)(&Xs[swz(lm, ks * 16 + kl * 8)]);
      __builtin_amdgcn_s_setprio(1);
      acc1[0] = MFMA32(af0, bf, acc1[0]);
      acc1[1] = MFMA32(af1, bf, acc1[1]);
      __builtin_amdgcn_s_setprio(0);
    }

    // ---- gelu -> Hs (f16x4 packed, swizzled) ----
    #pragma unroll
    for (int mi = 0; mi < 2; ++mi)
      #pragma unroll
      for (int q = 0; q < 4; ++q) {
        int hh = w * 64 + mi * 32 + q * 8 + kl * 4;
        f16x4 g;
        #pragma unroll
        for (int r = 0; r < 4; ++r) g[r] = (_Float16)gelu_fast(acc1[mi][q * 4 + r]);
        *(f16x4*)(&Hs[swz(lm, hh)]) = g;
      }

    if (ch == 0) {  // init acc2 with b2 (after acc1-ch0 dies: lower peak regs)
      #pragma unroll
      for (int mi = 0; mi < 2; ++mi)
        #pragma unroll
        for (int q = 0; q < 4; ++q) {
          f32x4 bv = *(const f32x4*)(b2 + w * 64 + mi * 32 + q * 8 + kl * 4);
          #pragma unroll
          for (int r = 0; r < 4; ++r) acc2[mi][q * 4 + r] = bv[r];
        }
    }
    BAR();  // Hs(ch) visible

    // ---- GEMM2 partial: s rows [w*64, +64), k = chb..chb+255 ----
    const _Float16* w2p = W2t + (size_t)(w * 64 + lm) * HID + chb + kl * 8;
    #pragma unroll
    for (int ks = 0; ks < 16; ++ks) {
      f16x8 af0 = *(const f16x8*)(w2p + ks * 16);
      f16x8 af1 = *(const f16x8*)(w2p + 32 * HID + ks * 16);
      f16x8 bf = *(const f16x8*)(&Hs[swz(lm, ks * 16 + kl * 8)]);
      __builtin_amdgcn_s_setprio(1);
      acc2[0] = MFMA32(af0, bf, acc2[0]);
      acc2[1] = MFMA32(af1, bf, acc2[1]);
      __builtin_amdgcn_s_setprio(0);
    }
    if (ch == 0) BAR();  // WAR: all waves done reading Hs(ch0) before overwrite
  }

  // ---- epilogue: time mask + fp32 store ----
  int t = t0 + lm;
  float m = (t < seqlen) ? 1.0f : 0.0f;
  #pragma unroll
  for (int mi = 0; mi < 2; ++mi)
    #pragma unroll
    for (int q = 0; q < 4; ++q) {
      int s0 = w * 64 + mi * 32 + q * 8 + kl * 4;
      #pragma unroll
      for (int r = 0; r < 4; ++r)
        out[((size_t)b * NSRC + s0 + r) * MAXT + t] = acc2[mi][q * 4 + r] * m;
    }
}

extern "C" void kernel_launch(void* const* d_in, const int* in_sizes, int n_in,
                              void* d_out, int out_size, void* d_ws, size_t ws_size,
                              hipStream_t stream) {
  const float* x      = (const float*)d_in[0];
  const int* sess     = (const int*)d_in[1];
  // d_in[2] = channel_counts: unused (x is already zero-padded past true channels)
  const int* seq      = (const int*)d_in[3];
  const float* W_sess = (const float*)d_in[4];
  const float* b_sess = (const float*)d_in[5];
  const float* W2     = (const float*)d_in[6];
  const float* b2     = (const float*)d_in[7];
  float* out = (float*)d_out;

  _Float16* W1t = (_Float16*)d_ws;                               // [8][512][256]
  _Float16* W2t = (_Float16*)((char*)d_ws + (size_t)8 * HID * MAXC * sizeof(_Float16));

  dim3 tb(32, 8);
  // W_sess: per session (256 x 512) -> (512 x 256) fp16
  transpose_cvt_kernel<<<dim3(HID / 32, MAXC / 32, 8), tb, 0, stream>>>(W_sess, W1t, MAXC, HID);
  // W2: (512 x 256) -> (256 x 512) fp16
  transpose_cvt_kernel<<<dim3(NSRC / 32, HID / 32, 1), tb, 0, stream>>>(W2, W2t, HID, NSRC);

  fused_sess_proj_kernel<<<dim3(NB * (MAXT / TT)), dim3(256), 0, stream>>>(
      x, sess, seq, W1t, b_sess, W2t, b2, out);
}

// Round 7
// 96.371 us; speedup vs baseline: 1.9403x; 1.5594x over previous
//
#include <hip/hip_runtime.h>

typedef __attribute__((ext_vector_type(8))) _Float16 f16x8;
typedef __attribute__((ext_vector_type(4))) _Float16 f16x4;
typedef __attribute__((ext_vector_type(2))) __fp16 fp16v2;  // cvt_pkrtz result type
typedef __attribute__((ext_vector_type(4))) float f32x4;

#define NB 16
#define MAXC 256
#define MAXT 4096
#define HID 512
#define NSRC 256

// LDS-visibility barrier (no vmcnt drain; compiler inserts vmcnt waits before
// the ds_writes that consume loaded registers).
#define BAR() asm volatile("s_waitcnt lgkmcnt(0)\n\ts_barrier" ::: "memory")

#define MFMA(a, b, c) __builtin_amdgcn_mfma_f32_16x16x32_f16(a, b, c, 0, 0, 0)

// gelu(x) ~= x * sigmoid(1.5957691x + 0.0713548x^3)   (tanh-form, |err| ~3e-4)
__device__ __forceinline__ float gelu_fast(float x) {
  float p = x * x;
  float q = __builtin_fmaf(p, -0.10294336f, -2.30220778f);
  float e = __builtin_amdgcn_exp2f(x * q);
  return x * __builtin_amdgcn_rcpf(1.0f + e);
}

// (R x C) fp32 -> (C x R) fp16, one 32x32 tile per block, blockIdx.z = matrix idx
__global__ void transpose_cvt_kernel(const float* __restrict__ src,
                                     _Float16* __restrict__ dst, int R, int C) {
  __shared__ float tile[32][33];
  const float* s = src + (size_t)blockIdx.z * R * C;
  _Float16* d = dst + (size_t)blockIdx.z * R * C;
  int c0 = blockIdx.x * 32, r0 = blockIdx.y * 32;
  int tx = threadIdx.x, ty = threadIdx.y;
  for (int i = ty; i < 32; i += 8)
    tile[i][tx] = s[(size_t)(r0 + i) * C + (c0 + tx)];
  __syncthreads();
  for (int i = ty; i < 32; i += 8)
    d[(size_t)(c0 + i) * R + (r0 + tx)] = (_Float16)tile[tx][i];
}

// LDS tiles are [128 rows][8 chunks of 8 f16]; chunk index XOR-swizzled by
// (row&7) so fragment reads (16 rows x same chunk) spread across all banks.

// ============ GEMM1: h_t[b][t][h] = gelu(W1t[sid] @ x[b] + b1) ============
// tile [128 h][128 t], K=256 in 4 steps of 64. 4 waves: wr=w>>1, wc=w&1.
__global__ __launch_bounds__(256, 3)
void gemm1_kernel(const float* __restrict__ x,
                  const int* __restrict__ sess_ids,
                  const int* __restrict__ seq_lens,
                  const _Float16* __restrict__ W1t,   // [8][HID][MAXC]
                  const float* __restrict__ b_sess,   // [8][HID]
                  _Float16* __restrict__ h_t) {       // [NB][MAXT][HID]
  int wg = blockIdx.x;
  int nt = wg & 31;
  int mt = (wg >> 5) & 3;
  int b = wg >> 7;
  int tb0 = nt * 128, h0 = mt * 128;
  int seqlen = seq_lens[b];
  if (tb0 >= seqlen) return;  // h_t left poisoned; GEMM2 never reads these tiles
  int sid = sess_ids[b];
  const _Float16* W = W1t + (size_t)sid * HID * MAXC + (size_t)h0 * MAXC;

  __shared__ _Float16 As[128 * 64];  // 16 KB  [h-row][c-chunk^swz]
  __shared__ _Float16 Bs[128 * 64];  // 16 KB  [t-row][c-chunk^swz]

  int tid = threadIdx.x;
  int lane = tid & 63, w = tid >> 6;
  int wr = w >> 1, wc = w & 1;
  int lg = lane >> 4, lr = lane & 15;

  f32x4 acc[4][4];
  #pragma unroll
  for (int mi = 0; mi < 4; ++mi) {
    f32x4 bv = *(const f32x4*)(b_sess + sid * HID + h0 + wr * 64 + mi * 16 + lg * 4);
    #pragma unroll
    for (int ni = 0; ni < 4; ++ni) acc[mi][ni] = bv;
  }

  int ar = tid >> 1, ah = tid & 1;         // A staging: row, col-half
  int c2 = (tid & 31) * 2, ts = tid >> 5;  // B staging: channel pair, 16-t slice

  #pragma unroll 1
  for (int kc = 0; kc < 4; ++kc) {
    int c0 = kc * 64;
    // ---- stage A (weights) ----
    {
      const _Float16* ga = W + (size_t)ar * MAXC + c0 + ah * 32;
      #pragma unroll
      for (int j = 0; j < 4; ++j) {
        f16x8 v = *(const f16x8*)(ga + j * 8);
        *(f16x8*)(&As[ar * 64 + (((ah * 4 + j) ^ (ar & 7)) * 8)]) = v;
      }
    }
    // ---- stage B (x transpose + cvt): channel-pair x 16 t per thread ----
    {
      const float* gx = x + ((size_t)b * MAXC + c0 + c2) * MAXT + tb0 + ts * 16;
      f32x4 va[4], vb[4];
      #pragma unroll
      for (int j = 0; j < 4; ++j) va[j] = *(const f32x4*)(gx + j * 4);
      #pragma unroll
      for (int j = 0; j < 4; ++j) vb[j] = *(const f32x4*)(gx + MAXT + j * 4);
      #pragma unroll
      for (int k = 0; k < 16; ++k) {
        int t = ts * 16 + k;
        fp16v2 p = __builtin_amdgcn_cvt_pkrtz(va[k >> 2][k & 3], vb[k >> 2][k & 3]);
        *(fp16v2*)(&Bs[t * 64 + (((c2 >> 3) ^ (t & 7)) * 8) + (c2 & 7)]) = p;
      }
    }
    BAR();  // tiles visible
    #pragma unroll
    for (int slot = 0; slot < 2; ++slot) {
      f16x8 af[4], bf[4];
      #pragma unroll
      for (int mi = 0; mi < 4; ++mi) {
        int row = wr * 64 + mi * 16 + lr;
        af[mi] = *(const f16x8*)(&As[row * 64 + (((slot * 4 + lg) ^ (row & 7)) * 8)]);
      }
      #pragma unroll
      for (int ni = 0; ni < 4; ++ni) {
        int t = wc * 64 + ni * 16 + lr;
        bf[ni] = *(const f16x8*)(&Bs[t * 64 + (((slot * 4 + lg) ^ (t & 7)) * 8)]);
      }
      __builtin_amdgcn_s_setprio(1);
      #pragma unroll
      for (int mi = 0; mi < 4; ++mi)
        #pragma unroll
        for (int ni = 0; ni < 4; ++ni)
          acc[mi][ni] = MFMA(af[mi], bf[ni], acc[mi][ni]);
      __builtin_amdgcn_s_setprio(0);
    }
    BAR();  // WAR before next stage
  }

  // ---- epilogue: gelu -> h_t fp16 [b][t][h] ----
  _Float16* hp = h_t + (size_t)b * MAXT * HID;
  #pragma unroll
  for (int mi = 0; mi < 4; ++mi) {
    int h = h0 + wr * 64 + mi * 16 + lg * 4;
    #pragma unroll
    for (int ni = 0; ni < 4; ++ni) {
      int t = tb0 + wc * 64 + ni * 16 + lr;
      f16x4 g;
      #pragma unroll
      for (int r = 0; r < 4; ++r) g[r] = (_Float16)gelu_fast(acc[mi][ni][r]);
      *(f16x4*)(hp + (size_t)t * HID + h) = g;
    }
  }
}

// ============ GEMM2: out[b][s][t] = (W2t @ h_t[b] + b2) * tmask ============
// tile [128 s][128 t], K=512 in 8 steps of 64. Same wave layout as GEMM1.
__global__ __launch_bounds__(256, 4)
void gemm2_kernel(const int* __restrict__ seq_lens,
                  const _Float16* __restrict__ W2t,   // [NSRC][HID]
                  const float* __restrict__ b2,       // [NSRC]
                  const _Float16* __restrict__ h_t,   // [NB][MAXT][HID]
                  float* __restrict__ out) {
  int wg = blockIdx.x;
  int nt = wg & 31;
  int mt = (wg >> 5) & 1;
  int b = wg >> 6;
  int tb0 = nt * 128, s0 = mt * 128;
  int seqlen = seq_lens[b];
  int tid = threadIdx.x;

  if (tb0 >= seqlen) {  // fully masked: write zeros, never touch h_t
    int sr = tid >> 1, tq = (tid & 1) * 64;
    float* po = out + ((size_t)b * NSRC + s0 + sr) * MAXT + tb0 + tq;
    f32x4 z = {0.f, 0.f, 0.f, 0.f};
    #pragma unroll
    for (int i = 0; i < 16; ++i) *(f32x4*)(po + i * 4) = z;
    return;
  }

  __shared__ _Float16 As[128 * 64];  // [s-row][h-chunk^swz]
  __shared__ _Float16 Bs[128 * 64];  // [t-row][h-chunk^swz]

  int lane = tid & 63, w = tid >> 6;
  int wr = w >> 1, wc = w & 1;
  int lg = lane >> 4, lr = lane & 15;

  f32x4 acc[4][4];
  #pragma unroll
  for (int mi = 0; mi < 4; ++mi) {
    f32x4 bv = *(const f32x4*)(b2 + s0 + wr * 64 + mi * 16 + lg * 4);
    #pragma unroll
    for (int ni = 0; ni < 4; ++ni) acc[mi][ni] = bv;
  }

  int ar = tid >> 1, ah = tid & 1;  // staging: row, col-half (both operands)
  const _Float16* WA = W2t + (size_t)(s0 + ar) * HID + ah * 32;
  const _Float16* HB = h_t + ((size_t)b * MAXT + tb0 + ar) * HID + ah * 32;

  #pragma unroll 1
  for (int kc = 0; kc < 8; ++kc) {
    int k0 = kc * 64;
    #pragma unroll
    for (int j = 0; j < 4; ++j) {
      f16x8 v = *(const f16x8*)(WA + k0 + j * 8);
      *(f16x8*)(&As[ar * 64 + (((ah * 4 + j) ^ (ar & 7)) * 8)]) = v;
    }
    #pragma unroll
    for (int j = 0; j < 4; ++j) {
      f16x8 v = *(const f16x8*)(HB + k0 + j * 8);
      *(f16x8*)(&Bs[ar * 64 + (((ah * 4 + j) ^ (ar & 7)) * 8)]) = v;
    }
    BAR();
    #pragma unroll
    for (int slot = 0; slot < 2; ++slot) {
      f16x8 af[4], bf[4];
      #pragma unroll
      for (int mi = 0; mi < 4; ++mi) {
        int row = wr * 64 + mi * 16 + lr;
        af[mi] = *(const f16x8*)(&As[row * 64 + (((slot * 4 + lg) ^ (row & 7)) * 8)]);
      }
      #pragma unroll
      for (int ni = 0; ni < 4; ++ni) {
        int t = wc * 64 + ni * 16 + lr;
        bf[ni] = *(const f16x8*)(&Bs[t * 64 + (((slot * 4 + lg) ^ (t & 7)) * 8)]);
      }
      __builtin_amdgcn_s_setprio(1);
      #pragma unroll
      for (int mi = 0; mi < 4; ++mi)
        #pragma unroll
        for (int ni = 0; ni < 4; ++ni)
          acc[mi][ni] = MFMA(af[mi], bf[ni], acc[mi][ni]);
      __builtin_amdgcn_s_setprio(0);
    }
    BAR();
  }

  // ---- epilogue: time mask + fp32 store ----
  #pragma unroll
  for (int mi = 0; mi < 4; ++mi) {
    int s = s0 + wr * 64 + mi * 16 + lg * 4;
    #pragma unroll
    for (int ni = 0; ni < 4; ++ni) {
      int t = tb0 + wc * 64 + ni * 16 + lr;
      float m = (t < seqlen) ? 1.0f : 0.0f;
      #pragma unroll
      for (int r = 0; r < 4; ++r)
        out[((size_t)b * NSRC + s + r) * MAXT + t] = acc[mi][ni][r] * m;
    }
  }
}

extern "C" void kernel_launch(void* const* d_in, const int* in_sizes, int n_in,
                              void* d_out, int out_size, void* d_ws, size_t ws_size,
                              hipStream_t stream) {
  const float* x      = (const float*)d_in[0];
  const int* sess     = (const int*)d_in[1];
  // d_in[2] = channel_counts: unused (x is already zero-padded past true channels)
  const int* seq      = (const int*)d_in[3];
  const float* W_sess = (const float*)d_in[4];
  const float* b_sess = (const float*)d_in[5];
  const float* W2     = (const float*)d_in[6];
  const float* b2     = (const float*)d_in[7];
  float* out = (float*)d_out;

  _Float16* W1t = (_Float16*)d_ws;                                   // 2 MB  [8][512][256]
  _Float16* W2t = (_Float16*)((char*)d_ws + (size_t)2 * 1024 * 1024);  // 256 KB [256][512]
  _Float16* h_t = (_Float16*)((char*)d_ws + (size_t)2 * 1024 * 1024 + 256 * 1024);  // 64 MB

  dim3 tb(32, 8);
  transpose_cvt_kernel<<<dim3(HID / 32, MAXC / 32, 8), tb, 0, stream>>>(W_sess, W1t, MAXC, HID);
  transpose_cvt_kernel<<<dim3(NSRC / 32, HID / 32, 1), tb, 0, stream>>>(W2, W2t, HID, NSRC);

  gemm1_kernel<<<dim3(NB * 4 * 32), dim3(256), 0, stream>>>(x, sess, seq, W1t, b_sess, h_t);
  gemm2_kernel<<<dim3(NB * 2 * 32), dim3(256), 0, stream>>>(seq, W2t, b2, h_t, out);
}

// Round 8
// 89.227 us; speedup vs baseline: 2.0956x; 1.0801x over previous
//
#include <hip/hip_runtime.h>

typedef __attribute__((ext_vector_type(8))) _Float16 f16x8;
typedef __attribute__((ext_vector_type(4))) _Float16 f16x4;
typedef __attribute__((ext_vector_type(2))) __fp16 fp16v2;  // cvt_pkrtz result type
typedef __attribute__((ext_vector_type(4))) float f32x4;

#define NB 16
#define MAXC 256
#define MAXT 4096
#define HID 512
#define NSRC 256

// LDS-visibility barrier (no vmcnt drain).
#define BAR() asm volatile("s_waitcnt lgkmcnt(0)\n\ts_barrier" ::: "memory")

#define MFMA(a, b, c) __builtin_amdgcn_mfma_f32_16x16x32_f16(a, b, c, 0, 0, 0)

// gelu(x) ~= x * sigmoid(1.5957691x + 0.0713548x^3)   (tanh-form, |err| ~3e-4)
__device__ __forceinline__ float gelu_fast(float x) {
  float p = x * x;
  float q = __builtin_fmaf(p, -0.10294336f, -2.30220778f);
  float e = __builtin_amdgcn_exp2f(x * q);
  return x * __builtin_amdgcn_rcpf(1.0f + e);
}

// (R x C) fp32 -> (C x R) fp16, one 32x32 tile per block, blockIdx.z = matrix idx
__global__ void transpose_cvt_kernel(const float* __restrict__ src,
                                     _Float16* __restrict__ dst, int R, int C) {
  __shared__ float tile[32][33];
  const float* s = src + (size_t)blockIdx.z * R * C;
  _Float16* d = dst + (size_t)blockIdx.z * R * C;
  int c0 = blockIdx.x * 32, r0 = blockIdx.y * 32;
  int tx = threadIdx.x, ty = threadIdx.y;
  for (int i = ty; i < 32; i += 8)
    tile[i][tx] = s[(size_t)(r0 + i) * C + (c0 + tx)];
  __syncthreads();
  for (int i = ty; i < 32; i += 8)
    d[(size_t)(c0 + i) * R + (r0 + tx)] = (_Float16)tile[tx][i];
}

// x [b][c][t] fp32 -> xT [b][t][c] fp16.  64x64 tiles, fully coalesced both
// sides.  Skips t-tiles >= ceil128(seqlen) (gemm1 reads in 128-t blocks; x is
// zero-padded past seqlen so covered tails are genuine zeros).
__global__ __launch_bounds__(256)
void transpose_x_kernel(const float* __restrict__ x,
                        const int* __restrict__ seq_lens,
                        _Float16* __restrict__ xT) {
  int b = blockIdx.z;
  int seqlen = seq_lens[b];
  int t0 = blockIdx.x * 64;
  if (t0 >= ((seqlen + 127) & ~127)) return;
  int c0 = blockIdx.y * 64;
  __shared__ float tile[64][65];
  int tid = threadIdx.x;
  int tx = tid & 63, ty = tid >> 6;
  const float* xp = x + ((size_t)b * MAXC + c0) * MAXT + t0;
  #pragma unroll
  for (int i = 0; i < 16; ++i) {
    int c = ty + i * 4;
    tile[c][tx] = xp[(size_t)c * MAXT + tx];
  }
  __syncthreads();
  int wt = tid >> 5;           // 0..7: t-row group
  int c2 = (tid & 31) * 2;     // channel pair
  _Float16* op = xT + ((size_t)b * MAXT + t0) * MAXC + c0;
  #pragma unroll
  for (int i = 0; i < 8; ++i) {
    int tl = wt + i * 8;
    fp16v2 p = __builtin_amdgcn_cvt_pkrtz(tile[c2][tl], tile[c2 + 1][tl]);
    *(fp16v2*)(op + (size_t)tl * MAXC + c2) = p;
  }
}

// LDS tiles are [128 rows][8 chunks of 8 f16]; chunk index XOR-swizzled by
// (row&7) so fragment reads (16 rows x same chunk) spread across all banks.

// ===== GEMM1: h_t[b][t][h] = gelu(W1t[sid] @ xT[b]^T + b1), tile 128x128 =====
__global__ __launch_bounds__(256, 4)
void gemm1_kernel(const _Float16* __restrict__ xT,   // [NB][MAXT][MAXC]
                  const int* __restrict__ sess_ids,
                  const int* __restrict__ seq_lens,
                  const _Float16* __restrict__ W1t,   // [8][HID][MAXC]
                  const float* __restrict__ b_sess,   // [8][HID]
                  _Float16* __restrict__ h_t) {       // [NB][MAXT][HID]
  int wg = blockIdx.x;
  int nt = wg & 31;
  int mt = (wg >> 5) & 3;
  int b = wg >> 7;
  int tb0 = nt * 128, h0 = mt * 128;
  int seqlen = seq_lens[b];
  if (tb0 >= seqlen) return;  // h_t left unwritten; gemm2 never reads these tiles
  int sid = sess_ids[b];

  __shared__ _Float16 As[128 * 64];  // 16 KB  [h-row][c-chunk^swz]
  __shared__ _Float16 Bs[128 * 64];  // 16 KB  [t-row][c-chunk^swz]

  int tid = threadIdx.x;
  int lane = tid & 63, w = tid >> 6;
  int wr = w >> 1, wc = w & 1;
  int lg = lane >> 4, lr = lane & 15;

  f32x4 acc[4][4];
  #pragma unroll
  for (int mi = 0; mi < 4; ++mi) {
    f32x4 bv = *(const f32x4*)(b_sess + sid * HID + h0 + wr * 64 + mi * 16 + lg * 4);
    #pragma unroll
    for (int ni = 0; ni < 4; ++ni) acc[mi][ni] = bv;
  }

  int ar = tid >> 1, ah = tid & 1;  // staging: row, col-half (both operands)
  const _Float16* WA = W1t + (size_t)sid * HID * MAXC + (size_t)(h0 + ar) * MAXC + ah * 32;
  const _Float16* HB = xT + ((size_t)b * MAXT + tb0 + ar) * MAXC + ah * 32;

  #pragma unroll 1
  for (int kc = 0; kc < 4; ++kc) {
    int k0 = kc * 64;
    #pragma unroll
    for (int j = 0; j < 4; ++j) {
      f16x8 v = *(const f16x8*)(WA + k0 + j * 8);
      *(f16x8*)(&As[ar * 64 + (((ah * 4 + j) ^ (ar & 7)) * 8)]) = v;
    }
    #pragma unroll
    for (int j = 0; j < 4; ++j) {
      f16x8 v = *(const f16x8*)(HB + k0 + j * 8);
      *(f16x8*)(&Bs[ar * 64 + (((ah * 4 + j) ^ (ar & 7)) * 8)]) = v;
    }
    BAR();
    #pragma unroll
    for (int slot = 0; slot < 2; ++slot) {
      f16x8 af[4], bf[4];
      #pragma unroll
      for (int mi = 0; mi < 4; ++mi) {
        int row = wr * 64 + mi * 16 + lr;
        af[mi] = *(const f16x8*)(&As[row * 64 + (((slot * 4 + lg) ^ (row & 7)) * 8)]);
      }
      #pragma unroll
      for (int ni = 0; ni < 4; ++ni) {
        int t = wc * 64 + ni * 16 + lr;
        bf[ni] = *(const f16x8*)(&Bs[t * 64 + (((slot * 4 + lg) ^ (t & 7)) * 8)]);
      }
      __builtin_amdgcn_s_setprio(1);
      #pragma unroll
      for (int mi = 0; mi < 4; ++mi)
        #pragma unroll
        for (int ni = 0; ni < 4; ++ni)
          acc[mi][ni] = MFMA(af[mi], bf[ni], acc[mi][ni]);
      __builtin_amdgcn_s_setprio(0);
    }
    BAR();
  }

  // ---- epilogue: gelu -> h_t fp16 [b][t][h] ----
  _Float16* hp = h_t + (size_t)b * MAXT * HID;
  #pragma unroll
  for (int mi = 0; mi < 4; ++mi) {
    int h = h0 + wr * 64 + mi * 16 + lg * 4;
    #pragma unroll
    for (int ni = 0; ni < 4; ++ni) {
      int t = tb0 + wc * 64 + ni * 16 + lr;
      f16x4 g;
      #pragma unroll
      for (int r = 0; r < 4; ++r) g[r] = (_Float16)gelu_fast(acc[mi][ni][r]);
      *(f16x4*)(hp + (size_t)t * HID + h) = g;
    }
  }
}

// ===== GEMM2: out[b][s][t] = (W2t @ h_t[b]^T + b2) * tmask, tile 128x128 =====
__global__ __launch_bounds__(256, 4)
void gemm2_kernel(const int* __restrict__ seq_lens,
                  const _Float16* __restrict__ W2t,   // [NSRC][HID]
                  const float* __restrict__ b2,       // [NSRC]
                  const _Float16* __restrict__ h_t,   // [NB][MAXT][HID]
                  float* __restrict__ out) {
  int wg = blockIdx.x;
  int nt = wg & 31;
  int mt = (wg >> 5) & 1;
  int b = wg >> 6;
  int tb0 = nt * 128, s0 = mt * 128;
  int seqlen = seq_lens[b];
  int tid = threadIdx.x;

  if (tb0 >= seqlen) {  // fully masked: write zeros, never touch h_t
    int sr = tid >> 1, tq = (tid & 1) * 64;
    float* po = out + ((size_t)b * NSRC + s0 + sr) * MAXT + tb0 + tq;
    f32x4 z = {0.f, 0.f, 0.f, 0.f};
    #pragma unroll
    for (int i = 0; i < 16; ++i) *(f32x4*)(po + i * 4) = z;
    return;
  }

  __shared__ _Float16 As[128 * 64];  // [s-row][h-chunk^swz]
  __shared__ _Float16 Bs[128 * 64];  // [t-row][h-chunk^swz]

  int lane = tid & 63, w = tid >> 6;
  int wr = w >> 1, wc = w & 1;
  int lg = lane >> 4, lr = lane & 15;

  f32x4 acc[4][4];
  #pragma unroll
  for (int mi = 0; mi < 4; ++mi) {
    f32x4 bv = *(const f32x4*)(b2 + s0 + wr * 64 + mi * 16 + lg * 4);
    #pragma unroll
    for (int ni = 0; ni < 4; ++ni) acc[mi][ni] = bv;
  }

  int ar = tid >> 1, ah = tid & 1;  // staging: row, col-half (both operands)
  const _Float16* WA = W2t + (size_t)(s0 + ar) * HID + ah * 32;
  const _Float16* HB = h_t + ((size_t)b * MAXT + tb0 + ar) * HID + ah * 32;

  #pragma unroll 1
  for (int kc = 0; kc < 8; ++kc) {
    int k0 = kc * 64;
    #pragma unroll
    for (int j = 0; j < 4; ++j) {
      f16x8 v = *(const f16x8*)(WA + k0 + j * 8);
      *(f16x8*)(&As[ar * 64 + (((ah * 4 + j) ^ (ar & 7)) * 8)]) = v;
    }
    #pragma unroll
    for (int j = 0; j < 4; ++j) {
      f16x8 v = *(const f16x8*)(HB + k0 + j * 8);
      *(f16x8*)(&Bs[ar * 64 + (((ah * 4 + j) ^ (ar & 7)) * 8)]) = v;
    }
    BAR();
    #pragma unroll
    for (int slot = 0; slot < 2; ++slot) {
      f16x8 af[4], bf[4];
      #pragma unroll
      for (int mi = 0; mi < 4; ++mi) {
        int row = wr * 64 + mi * 16 + lr;
        af[mi] = *(const f16x8*)(&As[row * 64 + (((slot * 4 + lg) ^ (row & 7)) * 8)]);
      }
      #pragma unroll
      for (int ni = 0; ni < 4; ++ni) {
        int t = wc * 64 + ni * 16 + lr;
        bf[ni] = *(const f16x8*)(&Bs[t * 64 + (((slot * 4 + lg) ^ (t & 7)) * 8)]);
      }
      __builtin_amdgcn_s_setprio(1);
      #pragma unroll
      for (int mi = 0; mi < 4; ++mi)
        #pragma unroll
        for (int ni = 0; ni < 4; ++ni)
          acc[mi][ni] = MFMA(af[mi], bf[ni], acc[mi][ni]);
      __builtin_amdgcn_s_setprio(0);
    }
    BAR();
  }

  // ---- epilogue: time mask + fp32 store ----
  #pragma unroll
  for (int mi = 0; mi < 4; ++mi) {
    int s = s0 + wr * 64 + mi * 16 + lg * 4;
    #pragma unroll
    for (int ni = 0; ni < 4; ++ni) {
      int t = tb0 + wc * 64 + ni * 16 + lr;
      float m = (t < seqlen) ? 1.0f : 0.0f;
      #pragma unroll
      for (int r = 0; r < 4; ++r)
        out[((size_t)b * NSRC + s + r) * MAXT + t] = acc[mi][ni][r] * m;
    }
  }
}

extern "C" void kernel_launch(void* const* d_in, const int* in_sizes, int n_in,
                              void* d_out, int out_size, void* d_ws, size_t ws_size,
                              hipStream_t stream) {
  const float* x      = (const float*)d_in[0];
  const int* sess     = (const int*)d_in[1];
  // d_in[2] = channel_counts: unused (x is already zero-padded past true channels)
  const int* seq      = (const int*)d_in[3];
  const float* W_sess = (const float*)d_in[4];
  const float* b_sess = (const float*)d_in[5];
  const float* W2     = (const float*)d_in[6];
  const float* b2     = (const float*)d_in[7];
  float* out = (float*)d_out;

  char* wp = (char*)d_ws;
  _Float16* W1t = (_Float16*)wp;                     wp += (size_t)8 * HID * MAXC * 2;   // 2 MB
  _Float16* W2t = (_Float16*)wp;                     wp += (size_t)NSRC * HID * 2;       // 256 KB
  _Float16* h_t = (_Float16*)wp;                     wp += (size_t)NB * MAXT * HID * 2;  // 64 MB
  _Float16* xT  = (_Float16*)wp;                                                          // 32 MB

  dim3 tb(32, 8);
  transpose_cvt_kernel<<<dim3(HID / 32, MAXC / 32, 8), tb, 0, stream>>>(W_sess, W1t, MAXC, HID);
  transpose_cvt_kernel<<<dim3(NSRC / 32, HID / 32, 1), tb, 0, stream>>>(W2, W2t, HID, NSRC);
  transpose_x_kernel<<<dim3(MAXT / 64, MAXC / 64, NB), dim3(256), 0, stream>>>(x, seq, xT);

  gemm1_kernel<<<dim3(NB * 4 * 32), dim3(256), 0, stream>>>(xT, sess, seq, W1t, b_sess, h_t);
  gemm2_kernel<<<dim3(NB * 2 * 32), dim3(256), 0, stream>>>(seq, W2t, b2, h_t, out);
}